// Round 13
// baseline (351.174 us; speedup 1.0000x reference)
//
#include <hip/hip_runtime.h>
#include <hip/hip_fp16.h>
#include <math.h>

#define NEG_SLOPE 0.2f
#define EPS_C 1e-16f

typedef _Float16 f16x8 __attribute__((ext_vector_type(8)));
typedef float f32x4 __attribute__((ext_vector_type(4)));

__device__ __forceinline__ float lrelu(float x){ return x > 0.f ? x : NEG_SLOPE * x; }
__device__ __forceinline__ float eluf(float x){ return x > 0.f ? x : expm1f(x); }

// ---------------- fused prep: x->fp16 | W1->fp16^T | W2->fp16^T | deg=0 ----------------
__global__ void prep_kernel(const float* __restrict__ x, __half* __restrict__ x16,
                            const float* __restrict__ W1, __half* __restrict__ W1t,
                            const float* __restrict__ W2, __half* __restrict__ W2t,
                            int* __restrict__ deg, int n4, int N){
  int i = blockIdx.x * blockDim.x + threadIdx.x;
  if (i < n4){
    float4 v = *reinterpret_cast<const float4*>(&x[(size_t)i * 4]);
    __half2 h01 = __floats2half2_rn(v.x, v.y);
    __half2 h23 = __floats2half2_rn(v.z, v.w);
    uint2 pack;
    pack.x = *reinterpret_cast<unsigned int*>(&h01);
    pack.y = *reinterpret_cast<unsigned int*>(&h23);
    *reinterpret_cast<uint2*>(&x16[(size_t)i * 4]) = pack;
    return;
  }
  int j = i - n4;
  if (j < 128 * 256){
    int k = j >> 8, c = j & 255;
    W1t[(size_t)c * 128 + k] = __float2half(W1[(size_t)k * 256 + c]);
    return;
  }
  j -= 128 * 256;
  if (j < 256 * 32){
    int k = j >> 5, c = j & 31;
    W2t[(size_t)c * 256 + k] = __float2half(W2[(size_t)k * 32 + c]);
    return;
  }
  j -= 256 * 32;
  if (j < N) deg[j] = 0;
}

// ---------------- fused: edge echo + degree count (single pass over ei) ----------------
__global__ void edge_deg_kernel(const int* __restrict__ ei, float* __restrict__ out1,
                                float* __restrict__ out3, int* __restrict__ deg,
                                int E, int n2e){
  int i = blockIdx.x * blockDim.x + threadIdx.x;
  if (i < n2e){
    int v = ei[i];
    float f = (float)v;
    out1[i] = f; out3[i] = f;
    if (i >= E) atomicAdd(&deg[v], 1);   // ei[E..2E) == dst
  }
}

__global__ __launch_bounds__(256) void scan1_kernel(const int* __restrict__ deg,
    int* __restrict__ offsets, int* __restrict__ blockSums, int N){
  __shared__ int sm[256];
  int b = blockIdx.x, t = threadIdx.x;
  int i = b * 256 + t;
  int v = (i < N) ? deg[i] : 0;
  sm[t] = v;
  __syncthreads();
  #pragma unroll
  for (int st = 1; st < 256; st <<= 1){
    int add = (t >= st) ? sm[t - st] : 0;
    __syncthreads();
    sm[t] += add;
    __syncthreads();
  }
  if (i < N) offsets[i] = sm[t] - v;
  if (t == 255) blockSums[b] = sm[255];
}

__global__ __launch_bounds__(256) void scan2_kernel(const int* __restrict__ blockSums,
    int* __restrict__ blockBase, int* __restrict__ offsetsN, int nb){
  __shared__ int sm[256];
  int t = threadIdx.x;
  int v = (t < nb) ? blockSums[t] : 0;
  sm[t] = v;
  __syncthreads();
  #pragma unroll
  for (int st = 1; st < 256; st <<= 1){
    int add = (t >= st) ? sm[t - st] : 0;
    __syncthreads();
    sm[t] += add;
    __syncthreads();
  }
  if (t < nb) blockBase[t] = sm[t] - v;
  if (t == 255) *offsetsN = sm[255];
}

__global__ __launch_bounds__(256) void scan3_kernel(int* __restrict__ offsets,
    const int* __restrict__ blockBase, int* __restrict__ cursor, int N){
  int b = blockIdx.x, t = threadIdx.x;
  int i = b * 256 + t;
  if (i < N){
    int v = offsets[i] + blockBase[b];
    offsets[i] = v;
    cursor[i] = v;
  }
}

__global__ void scatter_kernel(const int* __restrict__ src, const int* __restrict__ dst,
                               int* __restrict__ cursor, int* __restrict__ csr_src,
                               int* __restrict__ csr_eid, int E){
  int i = blockIdx.x * blockDim.x + threadIdx.x;
  if (i < E){
    int d = dst[i];
    int p = atomicAdd(&cursor[d], 1);
    csr_src[p] = src[i];
    csr_eid[p] = i;
  }
}

// ---------------- layer 1 GEMM via MFMA: h1 = x16 @ W1t ----------------
__global__ __launch_bounds__(256) void gemm1_kernel(const __half* __restrict__ x16,
    const __half* __restrict__ W1t, const float* __restrict__ att_src,
    const float* __restrict__ att_dst, __half* __restrict__ h1,
    float* __restrict__ a_src_f, float* __restrict__ a_dst_f, int N){
  __shared__ _Float16 As[128 * 136];
  __shared__ _Float16 Bs[64 * 136];
  int tid = threadIdx.x;
  int lane = tid & 63, wid = tid >> 6;
  int rowBase = blockIdx.x * 128;
  int head = blockIdx.y;
  int colBase = head * 64;

  #pragma unroll
  for (int it = 0; it < 8; ++it){
    int li = it * 256 + tid;
    int r = li >> 4, seg = li & 15;
    int grow = rowBase + r;
    f16x8 v = {};
    if (grow < N) v = *reinterpret_cast<const f16x8*>(&x16[(size_t)grow * 128 + seg * 8]);
    *reinterpret_cast<f16x8*>(&As[r * 136 + seg * 8]) = v;
  }
  #pragma unroll
  for (int it = 0; it < 4; ++it){
    int li = it * 256 + tid;
    int c = li >> 4, seg = li & 15;
    f16x8 v = *reinterpret_cast<const f16x8*>(&W1t[(size_t)(colBase + c) * 128 + seg * 8]);
    *reinterpret_cast<f16x8*>(&Bs[c * 136 + seg * 8]) = v;
  }
  __syncthreads();

  f32x4 acc[2][4] = {};
  int l15 = lane & 15, l4 = lane >> 4;
  #pragma unroll
  for (int ks = 0; ks < 4; ++ks){
    int kOff = ks * 32 + l4 * 8;
    f16x8 a0 = *reinterpret_cast<const f16x8*>(&As[(wid * 32 + l15) * 136 + kOff]);
    f16x8 a1 = *reinterpret_cast<const f16x8*>(&As[(wid * 32 + 16 + l15) * 136 + kOff]);
    #pragma unroll
    for (int cc = 0; cc < 4; ++cc){
      f16x8 b = *reinterpret_cast<const f16x8*>(&Bs[(cc * 16 + l15) * 136 + kOff]);
      acc[0][cc] = __builtin_amdgcn_mfma_f32_16x16x32_f16(a0, b, acc[0][cc], 0, 0, 0);
      acc[1][cc] = __builtin_amdgcn_mfma_f32_16x16x32_f16(a1, b, acc[1][cc], 0, 0, 0);
    }
  }

  #pragma unroll
  for (int rr = 0; rr < 2; ++rr){
    #pragma unroll
    for (int i = 0; i < 4; ++i){
      int row = rowBase + wid * 32 + rr * 16 + l4 * 4 + i;
      if (row < N){
        #pragma unroll
        for (int cc = 0; cc < 4; ++cc)
          h1[(size_t)row * 256 + colBase + cc * 16 + l15] = __float2half(acc[rr][cc][i]);
      }
    }
  }
  float sw[4], dw[4];
  #pragma unroll
  for (int cc = 0; cc < 4; ++cc){
    sw[cc] = att_src[colBase + cc * 16 + l15];
    dw[cc] = att_dst[colBase + cc * 16 + l15];
  }
  #pragma unroll
  for (int rr = 0; rr < 2; ++rr){
    #pragma unroll
    for (int i = 0; i < 4; ++i){
      float ts = 0.f, td = 0.f;
      #pragma unroll
      for (int cc = 0; cc < 4; ++cc){
        ts += acc[rr][cc][i] * sw[cc];
        td += acc[rr][cc][i] * dw[cc];
      }
      #pragma unroll
      for (int st = 8; st > 0; st >>= 1){
        ts += __shfl_xor(ts, st);
        td += __shfl_xor(td, st);
      }
      int row = rowBase + wid * 32 + rr * 16 + l4 * 4 + i;
      if (l15 == 0 && row < N){
        a_src_f[(size_t)row * 4 + head] = ts;
        a_dst_f[(size_t)row * 4 + head] = td;
      }
    }
  }
}

// ---------------- layer 1 node kernel ----------------
// R11 post-mortem: MLP-8 unroll raised VGPR 36->48, occupancy 65->45%,
// REGRESSED 82->97us (TLP was hiding latency, not ILP). Reverted to the
// R10-measured MLP-4 form. LDS-alpha cache + fp16 h1b kept (measured wins).
__global__ __launch_bounds__(256) void node1_kernel(
    const __half* __restrict__ h1, const float4* __restrict__ a_src,
    const float* __restrict__ a_src_f, const float4* __restrict__ a_dst,
    const int* __restrict__ offsets, const int* __restrict__ csr_src,
    const int* __restrict__ csr_eid, const float* __restrict__ bias,
    __half* __restrict__ h1b, float* __restrict__ alpha1_out, int N){
  __shared__ float al_lds[4][4][64];
  int gid = blockIdx.x * blockDim.x + threadIdx.x;
  int n = gid >> 6, lane = gid & 63, wid = (threadIdx.x >> 6) & 3;
  if (n >= N) return;
  int off = offsets[n];
  int deg = offsets[n + 1] - off;
  float4 ad = a_dst[n];
  bool have0 = (lane < deg);
  float4 e0 = make_float4(-INFINITY, -INFINITY, -INFINITY, -INFINITY);
  if (have0){
    float4 as = a_src[csr_src[off + lane]];
    e0 = make_float4(lrelu(as.x + ad.x), lrelu(as.y + ad.y),
                     lrelu(as.z + ad.z), lrelu(as.w + ad.w));
  }
  float m0 = e0.x, m1 = e0.y, m2 = e0.z, m3 = e0.w;
  for (int i = lane + 64; i < deg; i += 64){
    float4 as = a_src[csr_src[off + i]];
    m0 = fmaxf(m0, lrelu(as.x + ad.x));
    m1 = fmaxf(m1, lrelu(as.y + ad.y));
    m2 = fmaxf(m2, lrelu(as.z + ad.z));
    m3 = fmaxf(m3, lrelu(as.w + ad.w));
  }
  #pragma unroll
  for (int st = 32; st > 0; st >>= 1){
    m0 = fmaxf(m0, __shfl_xor(m0, st));
    m1 = fmaxf(m1, __shfl_xor(m1, st));
    m2 = fmaxf(m2, __shfl_xor(m2, st));
    m3 = fmaxf(m3, __shfl_xor(m3, st));
  }
  float s0 = 0.f, s1 = 0.f, s2 = 0.f, s3 = 0.f;
  if (have0){
    s0 = __expf(e0.x - m0); s1 = __expf(e0.y - m1);
    s2 = __expf(e0.z - m2); s3 = __expf(e0.w - m3);
  }
  for (int i = lane + 64; i < deg; i += 64){
    float4 as = a_src[csr_src[off + i]];
    s0 += __expf(lrelu(as.x + ad.x) - m0);
    s1 += __expf(lrelu(as.y + ad.y) - m1);
    s2 += __expf(lrelu(as.z + ad.z) - m2);
    s3 += __expf(lrelu(as.w + ad.w) - m3);
  }
  #pragma unroll
  for (int st = 32; st > 0; st >>= 1){
    s0 += __shfl_xor(s0, st); s1 += __shfl_xor(s1, st);
    s2 += __shfl_xor(s2, st); s3 += __shfl_xor(s3, st);
  }
  float i0 = 1.f / (s0 + EPS_C), i1 = 1.f / (s1 + EPS_C);
  float i2 = 1.f / (s2 + EPS_C), i3 = 1.f / (s3 + EPS_C);
  if (have0){
    float a0 = __expf(e0.x - m0) * i0, a1 = __expf(e0.y - m1) * i1;
    float a2 = __expf(e0.z - m2) * i2, a3 = __expf(e0.w - m3) * i3;
    al_lds[wid][0][lane] = a0; al_lds[wid][1][lane] = a1;
    al_lds[wid][2][lane] = a2; al_lds[wid][3][lane] = a3;
    int eid = csr_eid[off + lane];
    *reinterpret_cast<float4*>(&alpha1_out[(size_t)eid * 4]) = make_float4(a0, a1, a2, a3);
  }
  for (int i = lane + 64; i < deg; i += 64){
    int slot = off + i;
    float4 as = a_src[csr_src[slot]];
    int eid = csr_eid[slot];
    *reinterpret_cast<float4*>(&alpha1_out[(size_t)eid * 4]) =
        make_float4(__expf(lrelu(as.x + ad.x) - m0) * i0,
                    __expf(lrelu(as.y + ad.y) - m1) * i1,
                    __expf(lrelu(as.z + ad.z) - m2) * i2,
                    __expf(lrelu(as.w + ad.w) - m3) * i3);
  }
  // aggregation: MLP-4 with LDS alphas (j<64); fallback recompute beyond.
  int head = lane >> 4;
  float mh  = head == 0 ? m0 : head == 1 ? m1 : head == 2 ? m2 : m3;
  float ih  = head == 0 ? i0 : head == 1 ? i1 : head == 2 ? i2 : i3;
  float adh = head == 0 ? ad.x : head == 1 ? ad.y : head == 2 ? ad.z : ad.w;
  float4 accA = make_float4(0.f, 0.f, 0.f, 0.f);
  float4 accB = make_float4(0.f, 0.f, 0.f, 0.f);
  float4 accC = make_float4(0.f, 0.f, 0.f, 0.f);
  float4 accD = make_float4(0.f, 0.f, 0.f, 0.f);
  int degL = deg < 64 ? deg : 64;
  int j = 0;
  for (; j + 3 < degL; j += 4){
    int sA = csr_src[off + j];
    int sB = csr_src[off + j + 1];
    int sC = csr_src[off + j + 2];
    int sD = csr_src[off + j + 3];
    float alA = al_lds[wid][head][j];
    float alB = al_lds[wid][head][j + 1];
    float alC = al_lds[wid][head][j + 2];
    float alD = al_lds[wid][head][j + 3];
    float2 rA = *reinterpret_cast<const float2*>(&h1[(size_t)sA * 256 + lane * 4]);
    float2 rB = *reinterpret_cast<const float2*>(&h1[(size_t)sB * 256 + lane * 4]);
    float2 rC = *reinterpret_cast<const float2*>(&h1[(size_t)sC * 256 + lane * 4]);
    float2 rD = *reinterpret_cast<const float2*>(&h1[(size_t)sD * 256 + lane * 4]);
    float2 fA0 = __half22float2(*reinterpret_cast<__half2*>(&rA.x));
    float2 fA1 = __half22float2(*reinterpret_cast<__half2*>(&rA.y));
    float2 fB0 = __half22float2(*reinterpret_cast<__half2*>(&rB.x));
    float2 fB1 = __half22float2(*reinterpret_cast<__half2*>(&rB.y));
    float2 fC0 = __half22float2(*reinterpret_cast<__half2*>(&rC.x));
    float2 fC1 = __half22float2(*reinterpret_cast<__half2*>(&rC.y));
    float2 fD0 = __half22float2(*reinterpret_cast<__half2*>(&rD.x));
    float2 fD1 = __half22float2(*reinterpret_cast<__half2*>(&rD.y));
    accA.x += alA * fA0.x; accA.y += alA * fA0.y; accA.z += alA * fA1.x; accA.w += alA * fA1.y;
    accB.x += alB * fB0.x; accB.y += alB * fB0.y; accB.z += alB * fB1.x; accB.w += alB * fB1.y;
    accC.x += alC * fC0.x; accC.y += alC * fC0.y; accC.z += alC * fC1.x; accC.w += alC * fC1.y;
    accD.x += alD * fD0.x; accD.y += alD * fD0.y; accD.z += alD * fD1.x; accD.w += alD * fD1.y;
  }
  for (; j < degL; ++j){
    int sA = csr_src[off + j];
    float alA = al_lds[wid][head][j];
    float2 rA = *reinterpret_cast<const float2*>(&h1[(size_t)sA * 256 + lane * 4]);
    float2 fA0 = __half22float2(*reinterpret_cast<__half2*>(&rA.x));
    float2 fA1 = __half22float2(*reinterpret_cast<__half2*>(&rA.y));
    accA.x += alA * fA0.x; accA.y += alA * fA0.y; accA.z += alA * fA1.x; accA.w += alA * fA1.y;
  }
  for (; j < deg; ++j){   // rare deg>64 tail
    int sA = csr_src[off + j];
    float alA = __expf(lrelu(a_src_f[(size_t)sA * 4 + head] + adh) - mh) * ih;
    float2 rA = *reinterpret_cast<const float2*>(&h1[(size_t)sA * 256 + lane * 4]);
    float2 fA0 = __half22float2(*reinterpret_cast<__half2*>(&rA.x));
    float2 fA1 = __half22float2(*reinterpret_cast<__half2*>(&rA.y));
    accA.x += alA * fA0.x; accA.y += alA * fA0.y; accA.z += alA * fA1.x; accA.w += alA * fA1.y;
  }
  accA.x += accB.x + accC.x + accD.x;
  accA.y += accB.y + accC.y + accD.y;
  accA.z += accB.z + accC.z + accD.z;
  accA.w += accB.w + accC.w + accD.w;
  float4 b = *reinterpret_cast<const float4*>(&bias[lane * 4]);
  __half2 o01 = __floats2half2_rn(eluf(accA.x + b.x), eluf(accA.y + b.y));
  __half2 o23 = __floats2half2_rn(eluf(accA.z + b.z), eluf(accA.w + b.w));
  uint2 pack;
  pack.x = *reinterpret_cast<unsigned int*>(&o01);
  pack.y = *reinterpret_cast<unsigned int*>(&o23);
  *reinterpret_cast<uint2*>(&h1b[(size_t)n * 256 + lane * 4]) = pack;
}

// ---------------- layer 2 GEMM via MFMA: h2pre = h1b16 @ W2t ----------------
__global__ __launch_bounds__(256) void gemm2_kernel(const __half* __restrict__ h1b,
    const __half* __restrict__ W2t, const float* __restrict__ att_src2,
    const float* __restrict__ att_dst2, __half* __restrict__ h2pre,
    float* __restrict__ a_src2, float* __restrict__ a_dst2, int N){
  __shared__ _Float16 As[128 * 136];
  __shared__ _Float16 Bs[32 * 136];
  int tid = threadIdx.x;
  int lane = tid & 63, wid = tid >> 6;
  int rowBase = blockIdx.x * 128;
  int l15 = lane & 15, l4 = lane >> 4;
  f32x4 acc[2][2] = {};

  for (int kc = 0; kc < 2; ++kc){
    if (kc) __syncthreads();
    #pragma unroll
    for (int it = 0; it < 8; ++it){
      int li = it * 256 + tid;
      int r = li >> 4, seg = li & 15;
      int grow = rowBase + r;
      f16x8 v = {};
      if (grow < N) v = *reinterpret_cast<const f16x8*>(&h1b[(size_t)grow * 256 + kc * 128 + seg * 8]);
      *reinterpret_cast<f16x8*>(&As[r * 136 + seg * 8]) = v;
    }
    #pragma unroll
    for (int it = 0; it < 2; ++it){
      int li = it * 256 + tid;
      int c = li >> 4, seg = li & 15;
      f16x8 v = *reinterpret_cast<const f16x8*>(&W2t[(size_t)c * 256 + kc * 128 + seg * 8]);
      *reinterpret_cast<f16x8*>(&Bs[c * 136 + seg * 8]) = v;
    }
    __syncthreads();
    #pragma unroll
    for (int ks = 0; ks < 4; ++ks){
      int kOff = ks * 32 + l4 * 8;
      f16x8 a0 = *reinterpret_cast<const f16x8*>(&As[(wid * 32 + l15) * 136 + kOff]);
      f16x8 a1 = *reinterpret_cast<const f16x8*>(&As[(wid * 32 + 16 + l15) * 136 + kOff]);
      #pragma unroll
      for (int cb = 0; cb < 2; ++cb){
        f16x8 b = *reinterpret_cast<const f16x8*>(&Bs[(cb * 16 + l15) * 136 + kOff]);
        acc[0][cb] = __builtin_amdgcn_mfma_f32_16x16x32_f16(a0, b, acc[0][cb], 0, 0, 0);
        acc[1][cb] = __builtin_amdgcn_mfma_f32_16x16x32_f16(a1, b, acc[1][cb], 0, 0, 0);
      }
    }
  }
  #pragma unroll
  for (int rr = 0; rr < 2; ++rr){
    #pragma unroll
    for (int i = 0; i < 4; ++i){
      int row = rowBase + wid * 32 + rr * 16 + l4 * 4 + i;
      if (row < N){
        #pragma unroll
        for (int cb = 0; cb < 2; ++cb)
          h2pre[(size_t)row * 32 + cb * 16 + l15] = __float2half(acc[rr][cb][i]);
      }
    }
  }
  float sw0 = att_src2[l15], sw1 = att_src2[16 + l15];
  float dw0 = att_dst2[l15], dw1 = att_dst2[16 + l15];
  #pragma unroll
  for (int rr = 0; rr < 2; ++rr){
    #pragma unroll
    for (int i = 0; i < 4; ++i){
      float ts = acc[rr][0][i] * sw0 + acc[rr][1][i] * sw1;
      float td = acc[rr][0][i] * dw0 + acc[rr][1][i] * dw1;
      #pragma unroll
      for (int st = 8; st > 0; st >>= 1){
        ts += __shfl_xor(ts, st);
        td += __shfl_xor(td, st);
      }
      int row = rowBase + wid * 32 + rr * 16 + l4 * 4 + i;
      if (l15 == 0 && row < N){
        a_src2[row] = ts;
        a_dst2[row] = td;
      }
    }
  }
}

// ---------------- layer 2 node kernel (R10-measured simple form) ----------------
__global__ __launch_bounds__(256) void node2_kernel(
    const __half* __restrict__ h2pre, const float* __restrict__ a_src2,
    const float* __restrict__ a_dst2, const int* __restrict__ offsets,
    const int* __restrict__ csr_src, const int* __restrict__ csr_eid,
    const float* __restrict__ bias2, float* __restrict__ out_h2,
    float* __restrict__ alpha2_out, int N){
  __shared__ float al_lds[4][64];
  int gid = blockIdx.x * blockDim.x + threadIdx.x;
  int n = gid >> 6, lane = gid & 63, wid = (threadIdx.x >> 6) & 3;
  if (n >= N) return;
  int off = offsets[n], deg = offsets[n + 1] - off;
  float adn = a_dst2[n];
  bool have0 = (lane < deg);
  float e0 = -INFINITY;
  if (have0) e0 = lrelu(a_src2[csr_src[off + lane]] + adn);
  float m = e0;
  for (int i = lane + 64; i < deg; i += 64)
    m = fmaxf(m, lrelu(a_src2[csr_src[off + i]] + adn));
  #pragma unroll
  for (int st = 32; st > 0; st >>= 1) m = fmaxf(m, __shfl_xor(m, st));
  float s = have0 ? __expf(e0 - m) : 0.f;
  for (int i = lane + 64; i < deg; i += 64)
    s += __expf(lrelu(a_src2[csr_src[off + i]] + adn) - m);
  #pragma unroll
  for (int st = 32; st > 0; st >>= 1) s += __shfl_xor(s, st);
  float inv = 1.f / (s + EPS_C);
  if (have0){
    float al = __expf(e0 - m) * inv;
    al_lds[wid][lane] = al;
    alpha2_out[csr_eid[off + lane]] = al;
  }
  for (int i = lane + 64; i < deg; i += 64){
    int slot = off + i;
    alpha2_out[csr_eid[slot]] = __expf(lrelu(a_src2[csr_src[slot]] + adn) - m) * inv;
  }
  int c = lane & 31, half = lane >> 5;
  int degL = deg < 64 ? deg : 64;
  float acc = 0.f;
  int j = half;
  for (; j < degL; j += 2){
    int src = csr_src[off + j];
    acc += al_lds[wid][j] * __half2float(h2pre[(size_t)src * 32 + c]);
  }
  for (; j < deg; j += 2){   // rare deg>64 tail
    int src = csr_src[off + j];
    float al = __expf(lrelu(a_src2[src] + adn) - m) * inv;
    acc += al * __half2float(h2pre[(size_t)src * 32 + c]);
  }
  acc += __shfl_xor(acc, 32);
  if (lane < 32) out_h2[(size_t)n * 32 + c] = acc + bias2[c];
}

extern "C" void kernel_launch(void* const* d_in, const int* in_sizes, int n_in,
                              void* d_out, int out_size, void* d_ws, size_t ws_size,
                              hipStream_t stream){
  const float* x        = (const float*)d_in[0];
  const int*   ei       = (const int*)d_in[1];
  const float* W1       = (const float*)d_in[2];
  const float* att_src1 = (const float*)d_in[3];
  const float* att_dst1 = (const float*)d_in[4];
  const float* bias1    = (const float*)d_in[5];
  const float* W2       = (const float*)d_in[6];
  const float* att_src2 = (const float*)d_in[7];
  const float* att_dst2 = (const float*)d_in[8];
  const float* bias2    = (const float*)d_in[9];
  float* out = (float*)d_out;
  (void)n_in; (void)out_size; (void)ws_size;

  const int N = in_sizes[0] / 128;
  const int E = in_sizes[1] / 2;
  const int* src = ei;
  const int* dst = ei + E;
  const int nb = (N + 255) / 256;

  char* ws = (char*)d_ws;
  size_t o = 0;
  auto alloc = [&](size_t bytes) -> void* {
    void* p = ws + o;
    o += (bytes + 255) & ~(size_t)255;
    return p;
  };
  __half* h1      = (__half*)alloc((size_t)N * 256 * 2);
  __half* x16     = (__half*)alloc((size_t)N * 128 * 2);
  __half* W1t     = (__half*)alloc((size_t)256 * 128 * 2);
  __half* W2t     = (__half*)alloc((size_t)32 * 256 * 2);
  __half* h1b     = (__half*)alloc((size_t)N * 256 * 2);
  __half* h2pre   = (__half*)alloc((size_t)N * 32 * 2);
  float*  a_src1  = (float*)alloc((size_t)N * 16);
  float*  a_dst1  = (float*)alloc((size_t)N * 16);
  float*  a_src2  = (float*)alloc((size_t)N * 4);
  float*  a_dst2  = (float*)alloc((size_t)N * 4);
  int*    deg     = (int*)alloc((size_t)N * 4);
  int*    offsets = (int*)alloc((size_t)(N + 1) * 4);
  int*    cursor  = (int*)alloc((size_t)N * 4);
  int*    csr_src = (int*)alloc((size_t)E * 4);
  int*    csr_eid = (int*)alloc((size_t)E * 4);
  int*    blockSums = (int*)alloc(256 * 4);
  int*    blockBase = (int*)alloc(256 * 4);

  const size_t OFF1 = (size_t)N * 32;
  const size_t OFF2 = OFF1 + (size_t)2 * E;
  const size_t OFF3 = OFF2 + (size_t)E * 4;
  const size_t OFF4 = OFF3 + (size_t)2 * E;

  int n4 = (N * 128) / 4;
  int prepTotal = n4 + 128 * 256 + 256 * 32 + N;
  hipLaunchKernelGGL(prep_kernel, dim3((prepTotal + 255) / 256), dim3(256), 0, stream,
                     x, x16, W1, W1t, W2, W2t, deg, n4, N);
  hipLaunchKernelGGL(edge_deg_kernel, dim3((2 * E + 255) / 256), dim3(256), 0, stream,
                     ei, out + OFF1, out + OFF3, deg, E, 2 * E);
  hipLaunchKernelGGL(scan1_kernel, dim3(nb), dim3(256), 0, stream, deg, offsets, blockSums, N);
  hipLaunchKernelGGL(scan2_kernel, dim3(1), dim3(256), 0, stream, blockSums, blockBase,
                     offsets + N, nb);
  hipLaunchKernelGGL(scan3_kernel, dim3(nb), dim3(256), 0, stream, offsets, blockBase, cursor, N);
  hipLaunchKernelGGL(scatter_kernel, dim3((E + 255) / 256), dim3(256), 0, stream,
                     src, dst, cursor, csr_src, csr_eid, E);
  hipLaunchKernelGGL(gemm1_kernel, dim3((N + 127) / 128, 4), dim3(256), 0, stream,
                     x16, W1t, att_src1, att_dst1, h1, a_src1, a_dst1, N);
  hipLaunchKernelGGL(node1_kernel, dim3((N * 64 + 255) / 256), dim3(256), 0, stream,
                     h1, (const float4*)a_src1, (const float*)a_src1, (const float4*)a_dst1,
                     offsets, csr_src, csr_eid, bias1, h1b, out + OFF2, N);
  hipLaunchKernelGGL(gemm2_kernel, dim3((N + 127) / 128), dim3(256), 0, stream,
                     h1b, W2t, att_src2, att_dst2, h2pre, a_src2, a_dst2, N);
  hipLaunchKernelGGL(node2_kernel, dim3((N * 64 + 255) / 256), dim3(256), 0, stream,
                     h2pre, a_src2, a_dst2, offsets, csr_src, csr_eid, bias2,
                     out, out + OFF4, N);
}

// Round 14
// 349.217 us; speedup vs baseline: 1.0056x; 1.0056x over previous
//
#include <hip/hip_runtime.h>
#include <hip/hip_fp16.h>
#include <math.h>

#define NEG_SLOPE 0.2f
#define EPS_C 1e-16f

typedef _Float16 f16x8 __attribute__((ext_vector_type(8)));
typedef float f32x4 __attribute__((ext_vector_type(4)));

__device__ __forceinline__ float lrelu(float x){ return x > 0.f ? x : NEG_SLOPE * x; }
__device__ __forceinline__ float eluf(float x){ return x > 0.f ? x : expm1f(x); }

// ---------------- fused prep: x->fp16 | W1->fp16^T | W2->fp16^T | deg=0 ----------------
__global__ void prep_kernel(const float* __restrict__ x, __half* __restrict__ x16,
                            const float* __restrict__ W1, __half* __restrict__ W1t,
                            const float* __restrict__ W2, __half* __restrict__ W2t,
                            int* __restrict__ deg, int n4, int N){
  int i = blockIdx.x * blockDim.x + threadIdx.x;
  if (i < n4){
    float4 v = *reinterpret_cast<const float4*>(&x[(size_t)i * 4]);
    __half2 h01 = __floats2half2_rn(v.x, v.y);
    __half2 h23 = __floats2half2_rn(v.z, v.w);
    uint2 pack;
    pack.x = *reinterpret_cast<unsigned int*>(&h01);
    pack.y = *reinterpret_cast<unsigned int*>(&h23);
    *reinterpret_cast<uint2*>(&x16[(size_t)i * 4]) = pack;
    return;
  }
  int j = i - n4;
  if (j < 128 * 256){
    int k = j >> 8, c = j & 255;
    W1t[(size_t)c * 128 + k] = __float2half(W1[(size_t)k * 256 + c]);
    return;
  }
  j -= 128 * 256;
  if (j < 256 * 32){
    int k = j >> 5, c = j & 31;
    W2t[(size_t)c * 256 + k] = __float2half(W2[(size_t)k * 32 + c]);
    return;
  }
  j -= 256 * 32;
  if (j < N) deg[j] = 0;
}

// ---------------- fused: edge echo + degree count (single pass over ei) ----------------
__global__ void edge_deg_kernel(const int* __restrict__ ei, float* __restrict__ out1,
                                float* __restrict__ out3, int* __restrict__ deg,
                                int E, int n2e){
  int i = blockIdx.x * blockDim.x + threadIdx.x;
  if (i < n2e){
    int v = ei[i];
    float f = (float)v;
    out1[i] = f; out3[i] = f;
    if (i >= E) atomicAdd(&deg[v], 1);   // ei[E..2E) == dst
  }
}

__global__ __launch_bounds__(256) void scan1_kernel(const int* __restrict__ deg,
    int* __restrict__ offsets, int* __restrict__ blockSums, int N){
  __shared__ int sm[256];
  int b = blockIdx.x, t = threadIdx.x;
  int i = b * 256 + t;
  int v = (i < N) ? deg[i] : 0;
  sm[t] = v;
  __syncthreads();
  #pragma unroll
  for (int st = 1; st < 256; st <<= 1){
    int add = (t >= st) ? sm[t - st] : 0;
    __syncthreads();
    sm[t] += add;
    __syncthreads();
  }
  if (i < N) offsets[i] = sm[t] - v;
  if (t == 255) blockSums[b] = sm[255];
}

__global__ __launch_bounds__(256) void scan2_kernel(const int* __restrict__ blockSums,
    int* __restrict__ blockBase, int* __restrict__ offsetsN, int nb){
  __shared__ int sm[256];
  int t = threadIdx.x;
  int v = (t < nb) ? blockSums[t] : 0;
  sm[t] = v;
  __syncthreads();
  #pragma unroll
  for (int st = 1; st < 256; st <<= 1){
    int add = (t >= st) ? sm[t - st] : 0;
    __syncthreads();
    sm[t] += add;
    __syncthreads();
  }
  if (t < nb) blockBase[t] = sm[t] - v;
  if (t == 255) *offsetsN = sm[255];
}

__global__ __launch_bounds__(256) void scan3_kernel(int* __restrict__ offsets,
    const int* __restrict__ blockBase, int* __restrict__ cursor, int N){
  int b = blockIdx.x, t = threadIdx.x;
  int i = b * 256 + t;
  if (i < N){
    int v = offsets[i] + blockBase[b];
    offsets[i] = v;
    cursor[i] = v;
  }
}

// R13: pack (src,eid) into one int2 -> ONE random 8B write per edge instead of
// two random 4B writes to two arrays (halves scatter's touched 64B lines).
__global__ void scatter_kernel(const int* __restrict__ src, const int* __restrict__ dst,
                               int* __restrict__ cursor, int2* __restrict__ csr_pack, int E){
  int i = blockIdx.x * blockDim.x + threadIdx.x;
  if (i < E){
    int d = dst[i];
    int p = atomicAdd(&cursor[d], 1);
    csr_pack[p] = make_int2(src[i], i);
  }
}

// ---------------- layer 1 GEMM via MFMA: h1 = x16 @ W1t ----------------
__global__ __launch_bounds__(256) void gemm1_kernel(const __half* __restrict__ x16,
    const __half* __restrict__ W1t, const float* __restrict__ att_src,
    const float* __restrict__ att_dst, __half* __restrict__ h1,
    float* __restrict__ a_src_f, float* __restrict__ a_dst_f, int N){
  __shared__ _Float16 As[128 * 136];
  __shared__ _Float16 Bs[64 * 136];
  int tid = threadIdx.x;
  int lane = tid & 63, wid = tid >> 6;
  int rowBase = blockIdx.x * 128;
  int head = blockIdx.y;
  int colBase = head * 64;

  #pragma unroll
  for (int it = 0; it < 8; ++it){
    int li = it * 256 + tid;
    int r = li >> 4, seg = li & 15;
    int grow = rowBase + r;
    f16x8 v = {};
    if (grow < N) v = *reinterpret_cast<const f16x8*>(&x16[(size_t)grow * 128 + seg * 8]);
    *reinterpret_cast<f16x8*>(&As[r * 136 + seg * 8]) = v;
  }
  #pragma unroll
  for (int it = 0; it < 4; ++it){
    int li = it * 256 + tid;
    int c = li >> 4, seg = li & 15;
    f16x8 v = *reinterpret_cast<const f16x8*>(&W1t[(size_t)(colBase + c) * 128 + seg * 8]);
    *reinterpret_cast<f16x8*>(&Bs[c * 136 + seg * 8]) = v;
  }
  __syncthreads();

  f32x4 acc[2][4] = {};
  int l15 = lane & 15, l4 = lane >> 4;
  #pragma unroll
  for (int ks = 0; ks < 4; ++ks){
    int kOff = ks * 32 + l4 * 8;
    f16x8 a0 = *reinterpret_cast<const f16x8*>(&As[(wid * 32 + l15) * 136 + kOff]);
    f16x8 a1 = *reinterpret_cast<const f16x8*>(&As[(wid * 32 + 16 + l15) * 136 + kOff]);
    #pragma unroll
    for (int cc = 0; cc < 4; ++cc){
      f16x8 b = *reinterpret_cast<const f16x8*>(&Bs[(cc * 16 + l15) * 136 + kOff]);
      acc[0][cc] = __builtin_amdgcn_mfma_f32_16x16x32_f16(a0, b, acc[0][cc], 0, 0, 0);
      acc[1][cc] = __builtin_amdgcn_mfma_f32_16x16x32_f16(a1, b, acc[1][cc], 0, 0, 0);
    }
  }

  #pragma unroll
  for (int rr = 0; rr < 2; ++rr){
    #pragma unroll
    for (int i = 0; i < 4; ++i){
      int row = rowBase + wid * 32 + rr * 16 + l4 * 4 + i;
      if (row < N){
        #pragma unroll
        for (int cc = 0; cc < 4; ++cc)
          h1[(size_t)row * 256 + colBase + cc * 16 + l15] = __float2half(acc[rr][cc][i]);
      }
    }
  }
  float sw[4], dw[4];
  #pragma unroll
  for (int cc = 0; cc < 4; ++cc){
    sw[cc] = att_src[colBase + cc * 16 + l15];
    dw[cc] = att_dst[colBase + cc * 16 + l15];
  }
  #pragma unroll
  for (int rr = 0; rr < 2; ++rr){
    #pragma unroll
    for (int i = 0; i < 4; ++i){
      float ts = 0.f, td = 0.f;
      #pragma unroll
      for (int cc = 0; cc < 4; ++cc){
        ts += acc[rr][cc][i] * sw[cc];
        td += acc[rr][cc][i] * dw[cc];
      }
      #pragma unroll
      for (int st = 8; st > 0; st >>= 1){
        ts += __shfl_xor(ts, st);
        td += __shfl_xor(td, st);
      }
      int row = rowBase + wid * 32 + rr * 16 + l4 * 4 + i;
      if (l15 == 0 && row < N){
        a_src_f[(size_t)row * 4 + head] = ts;
        a_dst_f[(size_t)row * 4 + head] = td;
      }
    }
  }
}

// ---------------- layer 1 node kernel ----------------
// R13: exp values cached pre-reduce (pass-2 lane contribution IS the alpha
// numerator) -> pass 3 saves 4 transcendentals/lane. csr_pack int2 read once.
__global__ __launch_bounds__(256) void node1_kernel(
    const __half* __restrict__ h1, const float4* __restrict__ a_src,
    const float* __restrict__ a_src_f, const float4* __restrict__ a_dst,
    const int* __restrict__ offsets, const int2* __restrict__ csr_pack,
    const float* __restrict__ bias,
    __half* __restrict__ h1b, float* __restrict__ alpha1_out, int N){
  __shared__ float al_lds[4][4][64];
  int gid = blockIdx.x * blockDim.x + threadIdx.x;
  int n = gid >> 6, lane = gid & 63, wid = (threadIdx.x >> 6) & 3;
  if (n >= N) return;
  int off = offsets[n];
  int deg = offsets[n + 1] - off;
  float4 ad = a_dst[n];
  bool have0 = (lane < deg);
  int2 se0 = make_int2(0, 0);
  float4 e0 = make_float4(-INFINITY, -INFINITY, -INFINITY, -INFINITY);
  if (have0){
    se0 = csr_pack[off + lane];
    float4 as = a_src[se0.x];
    e0 = make_float4(lrelu(as.x + ad.x), lrelu(as.y + ad.y),
                     lrelu(as.z + ad.z), lrelu(as.w + ad.w));
  }
  float m0 = e0.x, m1 = e0.y, m2 = e0.z, m3 = e0.w;
  for (int i = lane + 64; i < deg; i += 64){
    float4 as = a_src[csr_pack[off + i].x];
    m0 = fmaxf(m0, lrelu(as.x + ad.x));
    m1 = fmaxf(m1, lrelu(as.y + ad.y));
    m2 = fmaxf(m2, lrelu(as.z + ad.z));
    m3 = fmaxf(m3, lrelu(as.w + ad.w));
  }
  #pragma unroll
  for (int st = 32; st > 0; st >>= 1){
    m0 = fmaxf(m0, __shfl_xor(m0, st));
    m1 = fmaxf(m1, __shfl_xor(m1, st));
    m2 = fmaxf(m2, __shfl_xor(m2, st));
    m3 = fmaxf(m3, __shfl_xor(m3, st));
  }
  // pass 2: exp cached (ex*) -- these ARE the alpha numerators for slot 0
  float ex0 = 0.f, ex1 = 0.f, ex2 = 0.f, ex3 = 0.f;
  if (have0){
    ex0 = __expf(e0.x - m0); ex1 = __expf(e0.y - m1);
    ex2 = __expf(e0.z - m2); ex3 = __expf(e0.w - m3);
  }
  float s0 = ex0, s1 = ex1, s2 = ex2, s3 = ex3;
  for (int i = lane + 64; i < deg; i += 64){
    float4 as = a_src[csr_pack[off + i].x];
    s0 += __expf(lrelu(as.x + ad.x) - m0);
    s1 += __expf(lrelu(as.y + ad.y) - m1);
    s2 += __expf(lrelu(as.z + ad.z) - m2);
    s3 += __expf(lrelu(as.w + ad.w) - m3);
  }
  #pragma unroll
  for (int st = 32; st > 0; st >>= 1){
    s0 += __shfl_xor(s0, st); s1 += __shfl_xor(s1, st);
    s2 += __shfl_xor(s2, st); s3 += __shfl_xor(s3, st);
  }
  float i0 = 1.f / (s0 + EPS_C), i1 = 1.f / (s1 + EPS_C);
  float i2 = 1.f / (s2 + EPS_C), i3 = 1.f / (s3 + EPS_C);
  // pass 3: alpha from cached exp (no recompute)
  if (have0){
    float a0 = ex0 * i0, a1 = ex1 * i1, a2 = ex2 * i2, a3 = ex3 * i3;
    al_lds[wid][0][lane] = a0; al_lds[wid][1][lane] = a1;
    al_lds[wid][2][lane] = a2; al_lds[wid][3][lane] = a3;
    *reinterpret_cast<float4*>(&alpha1_out[(size_t)se0.y * 4]) = make_float4(a0, a1, a2, a3);
  }
  for (int i = lane + 64; i < deg; i += 64){
    int2 se = csr_pack[off + i];
    float4 as = a_src[se.x];
    *reinterpret_cast<float4*>(&alpha1_out[(size_t)se.y * 4]) =
        make_float4(__expf(lrelu(as.x + ad.x) - m0) * i0,
                    __expf(lrelu(as.y + ad.y) - m1) * i1,
                    __expf(lrelu(as.z + ad.z) - m2) * i2,
                    __expf(lrelu(as.w + ad.w) - m3) * i3);
  }
  // aggregation: MLP-4 with LDS alphas (j<64); fallback recompute beyond.
  int head = lane >> 4;
  float mh  = head == 0 ? m0 : head == 1 ? m1 : head == 2 ? m2 : m3;
  float ih  = head == 0 ? i0 : head == 1 ? i1 : head == 2 ? i2 : i3;
  float adh = head == 0 ? ad.x : head == 1 ? ad.y : head == 2 ? ad.z : ad.w;
  float4 accA = make_float4(0.f, 0.f, 0.f, 0.f);
  float4 accB = make_float4(0.f, 0.f, 0.f, 0.f);
  float4 accC = make_float4(0.f, 0.f, 0.f, 0.f);
  float4 accD = make_float4(0.f, 0.f, 0.f, 0.f);
  int degL = deg < 64 ? deg : 64;
  int j = 0;
  for (; j + 3 < degL; j += 4){
    int sA = csr_pack[off + j].x;
    int sB = csr_pack[off + j + 1].x;
    int sC = csr_pack[off + j + 2].x;
    int sD = csr_pack[off + j + 3].x;
    float alA = al_lds[wid][head][j];
    float alB = al_lds[wid][head][j + 1];
    float alC = al_lds[wid][head][j + 2];
    float alD = al_lds[wid][head][j + 3];
    float2 rA = *reinterpret_cast<const float2*>(&h1[(size_t)sA * 256 + lane * 4]);
    float2 rB = *reinterpret_cast<const float2*>(&h1[(size_t)sB * 256 + lane * 4]);
    float2 rC = *reinterpret_cast<const float2*>(&h1[(size_t)sC * 256 + lane * 4]);
    float2 rD = *reinterpret_cast<const float2*>(&h1[(size_t)sD * 256 + lane * 4]);
    float2 fA0 = __half22float2(*reinterpret_cast<__half2*>(&rA.x));
    float2 fA1 = __half22float2(*reinterpret_cast<__half2*>(&rA.y));
    float2 fB0 = __half22float2(*reinterpret_cast<__half2*>(&rB.x));
    float2 fB1 = __half22float2(*reinterpret_cast<__half2*>(&rB.y));
    float2 fC0 = __half22float2(*reinterpret_cast<__half2*>(&rC.x));
    float2 fC1 = __half22float2(*reinterpret_cast<__half2*>(&rC.y));
    float2 fD0 = __half22float2(*reinterpret_cast<__half2*>(&rD.x));
    float2 fD1 = __half22float2(*reinterpret_cast<__half2*>(&rD.y));
    accA.x += alA * fA0.x; accA.y += alA * fA0.y; accA.z += alA * fA1.x; accA.w += alA * fA1.y;
    accB.x += alB * fB0.x; accB.y += alB * fB0.y; accB.z += alB * fB1.x; accB.w += alB * fB1.y;
    accC.x += alC * fC0.x; accC.y += alC * fC0.y; accC.z += alC * fC1.x; accC.w += alC * fC1.y;
    accD.x += alD * fD0.x; accD.y += alD * fD0.y; accD.z += alD * fD1.x; accD.w += alD * fD1.y;
  }
  for (; j < degL; ++j){
    int sA = csr_pack[off + j].x;
    float alA = al_lds[wid][head][j];
    float2 rA = *reinterpret_cast<const float2*>(&h1[(size_t)sA * 256 + lane * 4]);
    float2 fA0 = __half22float2(*reinterpret_cast<__half2*>(&rA.x));
    float2 fA1 = __half22float2(*reinterpret_cast<__half2*>(&rA.y));
    accA.x += alA * fA0.x; accA.y += alA * fA0.y; accA.z += alA * fA1.x; accA.w += alA * fA1.y;
  }
  for (; j < deg; ++j){   // rare deg>64 tail
    int sA = csr_pack[off + j].x;
    float alA = __expf(lrelu(a_src_f[(size_t)sA * 4 + head] + adh) - mh) * ih;
    float2 rA = *reinterpret_cast<const float2*>(&h1[(size_t)sA * 256 + lane * 4]);
    float2 fA0 = __half22float2(*reinterpret_cast<__half2*>(&rA.x));
    float2 fA1 = __half22float2(*reinterpret_cast<__half2*>(&rA.y));
    accA.x += alA * fA0.x; accA.y += alA * fA0.y; accA.z += alA * fA1.x; accA.w += alA * fA1.y;
  }
  accA.x += accB.x + accC.x + accD.x;
  accA.y += accB.y + accC.y + accD.y;
  accA.z += accB.z + accC.z + accD.z;
  accA.w += accB.w + accC.w + accD.w;
  float4 b = *reinterpret_cast<const float4*>(&bias[lane * 4]);
  __half2 o01 = __floats2half2_rn(eluf(accA.x + b.x), eluf(accA.y + b.y));
  __half2 o23 = __floats2half2_rn(eluf(accA.z + b.z), eluf(accA.w + b.w));
  uint2 pack;
  pack.x = *reinterpret_cast<unsigned int*>(&o01);
  pack.y = *reinterpret_cast<unsigned int*>(&o23);
  *reinterpret_cast<uint2*>(&h1b[(size_t)n * 256 + lane * 4]) = pack;
}

// ---------------- layer 2 GEMM via MFMA: h2pre = h1b16 @ W2t ----------------
__global__ __launch_bounds__(256) void gemm2_kernel(const __half* __restrict__ h1b,
    const __half* __restrict__ W2t, const float* __restrict__ att_src2,
    const float* __restrict__ att_dst2, __half* __restrict__ h2pre,
    float* __restrict__ a_src2, float* __restrict__ a_dst2, int N){
  __shared__ _Float16 As[128 * 136];
  __shared__ _Float16 Bs[32 * 136];
  int tid = threadIdx.x;
  int lane = tid & 63, wid = tid >> 6;
  int rowBase = blockIdx.x * 128;
  int l15 = lane & 15, l4 = lane >> 4;
  f32x4 acc[2][2] = {};

  for (int kc = 0; kc < 2; ++kc){
    if (kc) __syncthreads();
    #pragma unroll
    for (int it = 0; it < 8; ++it){
      int li = it * 256 + tid;
      int r = li >> 4, seg = li & 15;
      int grow = rowBase + r;
      f16x8 v = {};
      if (grow < N) v = *reinterpret_cast<const f16x8*>(&h1b[(size_t)grow * 256 + kc * 128 + seg * 8]);
      *reinterpret_cast<f16x8*>(&As[r * 136 + seg * 8]) = v;
    }
    #pragma unroll
    for (int it = 0; it < 2; ++it){
      int li = it * 256 + tid;
      int c = li >> 4, seg = li & 15;
      f16x8 v = *reinterpret_cast<const f16x8*>(&W2t[(size_t)c * 256 + kc * 128 + seg * 8]);
      *reinterpret_cast<f16x8*>(&Bs[c * 136 + seg * 8]) = v;
    }
    __syncthreads();
    #pragma unroll
    for (int ks = 0; ks < 4; ++ks){
      int kOff = ks * 32 + l4 * 8;
      f16x8 a0 = *reinterpret_cast<const f16x8*>(&As[(wid * 32 + l15) * 136 + kOff]);
      f16x8 a1 = *reinterpret_cast<const f16x8*>(&As[(wid * 32 + 16 + l15) * 136 + kOff]);
      #pragma unroll
      for (int cb = 0; cb < 2; ++cb){
        f16x8 b = *reinterpret_cast<const f16x8*>(&Bs[(cb * 16 + l15) * 136 + kOff]);
        acc[0][cb] = __builtin_amdgcn_mfma_f32_16x16x32_f16(a0, b, acc[0][cb], 0, 0, 0);
        acc[1][cb] = __builtin_amdgcn_mfma_f32_16x16x32_f16(a1, b, acc[1][cb], 0, 0, 0);
      }
    }
  }
  #pragma unroll
  for (int rr = 0; rr < 2; ++rr){
    #pragma unroll
    for (int i = 0; i < 4; ++i){
      int row = rowBase + wid * 32 + rr * 16 + l4 * 4 + i;
      if (row < N){
        #pragma unroll
        for (int cb = 0; cb < 2; ++cb)
          h2pre[(size_t)row * 32 + cb * 16 + l15] = __float2half(acc[rr][cb][i]);
      }
    }
  }
  float sw0 = att_src2[l15], sw1 = att_src2[16 + l15];
  float dw0 = att_dst2[l15], dw1 = att_dst2[16 + l15];
  #pragma unroll
  for (int rr = 0; rr < 2; ++rr){
    #pragma unroll
    for (int i = 0; i < 4; ++i){
      float ts = acc[rr][0][i] * sw0 + acc[rr][1][i] * sw1;
      float td = acc[rr][0][i] * dw0 + acc[rr][1][i] * dw1;
      #pragma unroll
      for (int st = 8; st > 0; st >>= 1){
        ts += __shfl_xor(ts, st);
        td += __shfl_xor(td, st);
      }
      int row = rowBase + wid * 32 + rr * 16 + l4 * 4 + i;
      if (l15 == 0 && row < N){
        a_src2[row] = ts;
        a_dst2[row] = td;
      }
    }
  }
}

// ---------------- layer 2 node kernel ----------------
__global__ __launch_bounds__(256) void node2_kernel(
    const __half* __restrict__ h2pre, const float* __restrict__ a_src2,
    const float* __restrict__ a_dst2, const int* __restrict__ offsets,
    const int2* __restrict__ csr_pack,
    const float* __restrict__ bias2, float* __restrict__ out_h2,
    float* __restrict__ alpha2_out, int N){
  __shared__ float al_lds[4][64];
  int gid = blockIdx.x * blockDim.x + threadIdx.x;
  int n = gid >> 6, lane = gid & 63, wid = (threadIdx.x >> 6) & 3;
  if (n >= N) return;
  int off = offsets[n], deg = offsets[n + 1] - off;
  float adn = a_dst2[n];
  bool have0 = (lane < deg);
  int2 se0 = make_int2(0, 0);
  float e0 = -INFINITY;
  if (have0){
    se0 = csr_pack[off + lane];
    e0 = lrelu(a_src2[se0.x] + adn);
  }
  float m = e0;
  for (int i = lane + 64; i < deg; i += 64)
    m = fmaxf(m, lrelu(a_src2[csr_pack[off + i].x] + adn));
  #pragma unroll
  for (int st = 32; st > 0; st >>= 1) m = fmaxf(m, __shfl_xor(m, st));
  float ex0 = have0 ? __expf(e0 - m) : 0.f;
  float s = ex0;
  for (int i = lane + 64; i < deg; i += 64)
    s += __expf(lrelu(a_src2[csr_pack[off + i].x] + adn) - m);
  #pragma unroll
  for (int st = 32; st > 0; st >>= 1) s += __shfl_xor(s, st);
  float inv = 1.f / (s + EPS_C);
  if (have0){
    float al = ex0 * inv;
    al_lds[wid][lane] = al;
    alpha2_out[se0.y] = al;
  }
  for (int i = lane + 64; i < deg; i += 64){
    int2 se = csr_pack[off + i];
    alpha2_out[se.y] = __expf(lrelu(a_src2[se.x] + adn) - m) * inv;
  }
  int c = lane & 31, half = lane >> 5;
  int degL = deg < 64 ? deg : 64;
  float acc = 0.f;
  int j = half;
  for (; j < degL; j += 2){
    int src = csr_pack[off + j].x;
    acc += al_lds[wid][j] * __half2float(h2pre[(size_t)src * 32 + c]);
  }
  for (; j < deg; j += 2){   // rare deg>64 tail
    int src = csr_pack[off + j].x;
    float al = __expf(lrelu(a_src2[src] + adn) - m) * inv;
    acc += al * __half2float(h2pre[(size_t)src * 32 + c]);
  }
  acc += __shfl_xor(acc, 32);
  if (lane < 32) out_h2[(size_t)n * 32 + c] = acc + bias2[c];
}

extern "C" void kernel_launch(void* const* d_in, const int* in_sizes, int n_in,
                              void* d_out, int out_size, void* d_ws, size_t ws_size,
                              hipStream_t stream){
  const float* x        = (const float*)d_in[0];
  const int*   ei       = (const int*)d_in[1];
  const float* W1       = (const float*)d_in[2];
  const float* att_src1 = (const float*)d_in[3];
  const float* att_dst1 = (const float*)d_in[4];
  const float* bias1    = (const float*)d_in[5];
  const float* W2       = (const float*)d_in[6];
  const float* att_src2 = (const float*)d_in[7];
  const float* att_dst2 = (const float*)d_in[8];
  const float* bias2    = (const float*)d_in[9];
  float* out = (float*)d_out;
  (void)n_in; (void)out_size; (void)ws_size;

  const int N = in_sizes[0] / 128;
  const int E = in_sizes[1] / 2;
  const int* src = ei;
  const int* dst = ei + E;
  const int nb = (N + 255) / 256;

  char* ws = (char*)d_ws;
  size_t o = 0;
  auto alloc = [&](size_t bytes) -> void* {
    void* p = ws + o;
    o += (bytes + 255) & ~(size_t)255;
    return p;
  };
  __half* h1      = (__half*)alloc((size_t)N * 256 * 2);
  __half* x16     = (__half*)alloc((size_t)N * 128 * 2);
  __half* W1t     = (__half*)alloc((size_t)256 * 128 * 2);
  __half* W2t     = (__half*)alloc((size_t)32 * 256 * 2);
  __half* h1b     = (__half*)alloc((size_t)N * 256 * 2);
  __half* h2pre   = (__half*)alloc((size_t)N * 32 * 2);
  float*  a_src1  = (float*)alloc((size_t)N * 16);
  float*  a_dst1  = (float*)alloc((size_t)N * 16);
  float*  a_src2  = (float*)alloc((size_t)N * 4);
  float*  a_dst2  = (float*)alloc((size_t)N * 4);
  int*    deg     = (int*)alloc((size_t)N * 4);
  int*    offsets = (int*)alloc((size_t)(N + 1) * 4);
  int*    cursor  = (int*)alloc((size_t)N * 4);
  int2*   csr_pack= (int2*)alloc((size_t)E * 8);
  int*    blockSums = (int*)alloc(256 * 4);
  int*    blockBase = (int*)alloc(256 * 4);

  const size_t OFF1 = (size_t)N * 32;
  const size_t OFF2 = OFF1 + (size_t)2 * E;
  const size_t OFF3 = OFF2 + (size_t)E * 4;
  const size_t OFF4 = OFF3 + (size_t)2 * E;

  int n4 = (N * 128) / 4;
  int prepTotal = n4 + 128 * 256 + 256 * 32 + N;
  hipLaunchKernelGGL(prep_kernel, dim3((prepTotal + 255) / 256), dim3(256), 0, stream,
                     x, x16, W1, W1t, W2, W2t, deg, n4, N);
  hipLaunchKernelGGL(edge_deg_kernel, dim3((2 * E + 255) / 256), dim3(256), 0, stream,
                     ei, out + OFF1, out + OFF3, deg, E, 2 * E);
  hipLaunchKernelGGL(scan1_kernel, dim3(nb), dim3(256), 0, stream, deg, offsets, blockSums, N);
  hipLaunchKernelGGL(scan2_kernel, dim3(1), dim3(256), 0, stream, blockSums, blockBase,
                     offsets + N, nb);
  hipLaunchKernelGGL(scan3_kernel, dim3(nb), dim3(256), 0, stream, offsets, blockBase, cursor, N);
  hipLaunchKernelGGL(scatter_kernel, dim3((E + 255) / 256), dim3(256), 0, stream,
                     src, dst, cursor, csr_pack, E);
  hipLaunchKernelGGL(gemm1_kernel, dim3((N + 127) / 128, 4), dim3(256), 0, stream,
                     x16, W1t, att_src1, att_dst1, h1, a_src1, a_dst1, N);
  hipLaunchKernelGGL(node1_kernel, dim3((N * 64 + 255) / 256), dim3(256), 0, stream,
                     h1, (const float4*)a_src1, (const float*)a_src1, (const float4*)a_dst1,
                     offsets, csr_pack, bias1, h1b, out + OFF2, N);
  hipLaunchKernelGGL(gemm2_kernel, dim3((N + 127) / 128), dim3(256), 0, stream,
                     h1b, W2t, att_src2, att_dst2, h2pre, a_src2, a_dst2, N);
  hipLaunchKernelGGL(node2_kernel, dim3((N * 64 + 255) / 256), dim3(256), 0, stream,
                     h2pre, a_src2, a_dst2, offsets, csr_pack, bias2,
                     out, out + OFF4, N);
}